// Round 1
// 3091.329 us; speedup vs baseline: 1.0902x; 1.0902x over previous
//
#include <hip/hip_runtime.h>
#include <hip/hip_bf16.h>
#include <cstdint>

// Problem constants
#define V_  32000
#define E_  512
#define H_  1024
#define CTX_ 1024
#define T_  64
#define B_  64
#define FH_ 4096   // 4*H
#define NRB 128    // persistent recurrence blocks (<= 256 CUs -> co-resident)

typedef __attribute__((ext_vector_type(8))) __bf16 bf16x8;
typedef __attribute__((ext_vector_type(4))) __bf16 bf16x4;
typedef __attribute__((ext_vector_type(4))) float f32x4;

#define DEV static __device__ __forceinline__

DEV __bf16 f2bf(float f) {
    union { float f; unsigned u; } v; v.f = f;
    unsigned r = (v.u + 0x7FFFu + ((v.u >> 16) & 1u)) >> 16;
    unsigned short s = (unsigned short)r;
    return __builtin_bit_cast(__bf16, s);
}

DEV float sigm(float x) { return 1.0f / (1.0f + __expf(-x)); }

// async global->LDS, 16B per lane; LDS dest = wave-uniform base + lane*16
#define GL(g, l) __builtin_amdgcn_global_load_lds(                         \
    (const __attribute__((address_space(1))) void*)(g),                    \
    (__attribute__((address_space(3))) void*)(l), 16, 0, 0)

// ---------------- casts / gathers ----------------
__global__ __launch_bounds__(256) void k_cast(const float* __restrict__ src,
                                              __bf16* __restrict__ dst, int n4) {
    int i = blockIdx.x * 256 + threadIdx.x;
    if (i >= n4) return;
    float4 v = *(const float4*)(src + (size_t)i * 4);
    bf16x4 o; o[0]=f2bf(v.x); o[1]=f2bf(v.y); o[2]=f2bf(v.z); o[3]=f2bf(v.w);
    *(bf16x4*)(dst + (size_t)i * 4) = o;
}

// W_ihE = bf16(W_ih[:, CTX:CTX+E])  -> [4096][512]
__global__ __launch_bounds__(256) void k_cast_wihe(const float* __restrict__ Wih,
                                                   __bf16* __restrict__ dst) {
    int i = blockIdx.x * 256 + threadIdx.x;   // 524288 threads, 4 elems each
    int e = i * 4, j = e >> 9, k = e & 511;
    float4 v = *(const float4*)(Wih + (size_t)j * (CTX_ + E_) + CTX_ + k);
    bf16x4 o; o[0]=f2bf(v.x); o[1]=f2bf(v.y); o[2]=f2bf(v.z); o[3]=f2bf(v.w);
    *(bf16x4*)(dst + (size_t)e) = o;
}

// X[t*64+b][k] = bf16(emb[seq[t*64+b]][k])  -> [4096][512]
__global__ __launch_bounds__(256) void k_gather_x(const int* __restrict__ seq,
                                                  const float* __restrict__ emb,
                                                  __bf16* __restrict__ dst) {
    int i = blockIdx.x * 256 + threadIdx.x;
    int e = i * 4, r = e >> 9, k = e & 511;
    int tok = seq[r];
    float4 v = *(const float4*)(emb + (size_t)tok * E_ + k);
    bf16x4 o; o[0]=f2bf(v.x); o[1]=f2bf(v.y); o[2]=f2bf(v.z); o[3]=f2bf(v.w);
    *(bf16x4*)(dst + (size_t)e) = o;
}

// ---------------- init state: h0 (bf16) , c0 (f32) ----------------
__global__ __launch_bounds__(256) void k_init(const float* __restrict__ ctx,
                                              const float* __restrict__ WS, const float* __restrict__ bS,
                                              const float* __restrict__ WC, const float* __restrict__ bC,
                                              __bf16* __restrict__ h0, float* __restrict__ c0) {
    int idx = blockIdx.x * 256 + threadIdx.x;   // 32768
    int r = idx >> 4, bg = idx & 15;
    int sel = r >> 10, u = r & 1023;
    const float4* w = (const float4*)((sel ? WC : WS) + (size_t)u * CTX_);
    float acc[4] = {0.f,0.f,0.f,0.f};
    for (int k = 0; k < 256; ++k) {
        float4 wv = w[k];
#pragma unroll
        for (int i = 0; i < 4; ++i) {
            float4 cv = *(const float4*)(ctx + (size_t)(bg + 16*i) * CTX_ + k * 4);
            acc[i] += wv.x*cv.x + wv.y*cv.y + wv.z*cv.z + wv.w*cv.w;
        }
    }
    float bias = sel ? bC[u] : bS[u];
#pragma unroll
    for (int i = 0; i < 4; ++i) {
        int b = bg + 16*i;
        float v = tanhf(acc[i] + bias);
        if (sel) c0[(size_t)b * H_ + u] = v;
        else     h0[(size_t)b * H_ + u] = f2bf(v);
    }
}

// ---------------- ctx_gates[b][j] = ctx[b]·W_ih[j][0:CTX] + b_ih[j] + b_hh[j] ----------------
__global__ __launch_bounds__(256) void k_ctxgates(const float* __restrict__ ctx,
                                                  const float* __restrict__ Wih,
                                                  const float* __restrict__ bih,
                                                  const float* __restrict__ bhh,
                                                  float* __restrict__ out) {
    int idx = blockIdx.x * 256 + threadIdx.x;   // 65536
    int j = idx >> 4, bg = idx & 15;
    const float4* w = (const float4*)(Wih + (size_t)j * (CTX_ + E_));
    float acc[4] = {0.f,0.f,0.f,0.f};
    for (int k = 0; k < 256; ++k) {
        float4 wv = w[k];
#pragma unroll
        for (int i = 0; i < 4; ++i) {
            float4 cv = *(const float4*)(ctx + (size_t)(bg + 16*i) * CTX_ + k * 4);
            acc[i] += wv.x*cv.x + wv.y*cv.y + wv.z*cv.z + wv.w*cv.w;
        }
    }
    float bias = bih[j] + bhh[j];
#pragma unroll
    for (int i = 0; i < 4; ++i) out[(size_t)(bg + 16*i) * FH_ + j] = acc[i] + bias;
}

// ---------------- barrier state zero ----------------
__global__ __launch_bounds__(1024) void k_zero(unsigned* __restrict__ bar) {
    bar[threadIdx.x] = 0u;
}

// ---------------- persistent recurrence kernel ----------------
// 128 blocks x 512 threads. Block owns u in [blockIdx*8, blockIdx*8+8)
// (32 gate columns: 4 gates x 8 units). Weights live in registers:
// wave w holds B-fragments for K-slice [w*192, w*192+192) -> 48 VGPRs/lane.
// c-state: 1 register per thread (thread owns (b = tid>>3, ul = tid&7)).
// Per step: MFMA partials -> LDS 8-way reduce -> cell update -> grid barrier.
__global__ __launch_bounds__(512, 2) void k_rnn(
    const __bf16* __restrict__ Whh, const __bf16* __restrict__ WihE,
    const __bf16* __restrict__ Xb, const float* __restrict__ ctxg,
    const float* __restrict__ c0,
    __bf16* __restrict__ hb0, __bf16* __restrict__ hb1,
    __bf16* __restrict__ HC, unsigned* __restrict__ bar)
{
    __shared__ float red[8][64][36];   // stride 36 -> conflict-free-ish (4b+n pattern)
    const int tid = threadIdx.x;
    const int w = tid >> 6, lane = tid & 63;
    const int fr = lane & 15, fq = lane >> 4;
    const int u0 = (int)blockIdx.x * 8;
    const int kb = w * 192;            // this wave's K-slice base (of 1536)

    // ---- one-time: B fragments into registers (48 VGPRs) ----
    bf16x8 breg[2][6];
#pragma unroll
    for (int ni = 0; ni < 2; ++ni) {
        const int n = ni * 16 + fr;                       // output col 0..31
        const int j = (n >> 3) * H_ + u0 + (n & 7);       // gate row in [0,4096)
#pragma unroll
        for (int ks = 0; ks < 6; ++ks) {
            const int k = kb + ks * 32;
            const __bf16* src = (k < H_) ? (Whh + (size_t)j * H_ + k)
                                         : (WihE + (size_t)j * E_ + (k - H_));
            breg[ni][ks] = *(const bf16x8*)(src + fq * 8);
        }
    }
    // ---- one-time: cell state + ctx-gate biases into registers ----
    const int cb = tid >> 3, cul = tid & 7, u = u0 + cul;
    float creg = c0[(size_t)cb * H_ + u];
    float cg[4];
#pragma unroll
    for (int g = 0; g < 4; ++g) cg[g] = ctxg[(size_t)cb * FH_ + g * H_ + u];

#pragma unroll 1
    for (int t = 0; t < T_; ++t) {
        const __bf16* h_in  = (t & 1) ? hb1 : hb0;
        __bf16*       h_out = (t & 1) ? hb0 : hb1;
        const __bf16* Xt = Xb + (size_t)t * (B_ * E_);

        f32x4 acc[4][2];
#pragma unroll
        for (int mi = 0; mi < 4; ++mi)
#pragma unroll
            for (int ni = 0; ni < 2; ++ni) acc[mi][ni] = (f32x4){0.f,0.f,0.f,0.f};

        // partial GEMM over this wave's K-slice; A straight from L2/LLC
#pragma unroll
        for (int ks = 0; ks < 6; ++ks) {
            const int k = kb + ks * 32;
            bf16x8 af[4];
#pragma unroll
            for (int mi = 0; mi < 4; ++mi) {
                const int row = mi * 16 + fr;             // batch row
                const __bf16* src = (k < H_) ? (h_in + (size_t)row * H_ + k)
                                             : (Xt + (size_t)row * E_ + (k - H_));
                af[mi] = *(const bf16x8*)(src + fq * 8);
            }
#pragma unroll
            for (int mi = 0; mi < 4; ++mi)
#pragma unroll
                for (int ni = 0; ni < 2; ++ni)
                    acc[mi][ni] = __builtin_amdgcn_mfma_f32_16x16x32_bf16(
                        af[mi], breg[ni][ks], acc[mi][ni], 0, 0, 0);
        }
        // partials -> LDS  (C/D frag: col=lane&15, row=fq*4+r)
#pragma unroll
        for (int mi = 0; mi < 4; ++mi)
#pragma unroll
            for (int ni = 0; ni < 2; ++ni)
#pragma unroll
                for (int r = 0; r < 4; ++r)
                    red[w][mi * 16 + fq * 4 + r][ni * 16 + fr] = acc[mi][ni][r];
        __syncthreads();

        // 8-way reduce + fused cell update; thread owns (cb, cul)
        float gv[4];
#pragma unroll
        for (int g = 0; g < 4; ++g) {
            float s = cg[g];
#pragma unroll
            for (int wv = 0; wv < 8; ++wv) s += red[wv][cb][g * 8 + cul];
            gv[g] = s;
        }
        const float cn = sigm(gv[1]) * creg + sigm(gv[0]) * tanhf(gv[2]);
        const float hn = sigm(gv[3]) * tanhf(cn);
        creg = cn;
        h_out[(size_t)cb * H_ + u] = f2bf(hn);
        __bf16* hc = HC + (size_t)t * (B_ * 2 * H_);
        hc[(size_t)cb * 2048 + u]      = f2bf(hn);
        hc[(size_t)cb * 2048 + H_ + u] = f2bf(cn);

        // ---- grid barrier (device-scope) ----
        __syncthreads();   // all waves' stores drained to L2 (vmcnt before s_barrier)
        if (tid == 0) {
            unsigned* b4 = bar + t * 16;   // 64B-strided counters
            __hip_atomic_fetch_add(b4, 1u, __ATOMIC_RELEASE, __HIP_MEMORY_SCOPE_AGENT);
            while (__hip_atomic_load(b4, __ATOMIC_ACQUIRE, __HIP_MEMORY_SCOPE_AGENT) < (unsigned)NRB)
                __builtin_amdgcn_s_sleep(1);
        }
        __syncthreads();
        __threadfence();   // acquire for all waves: L1/L2 inv before next h reads
    }
}

// ---------------- d1 GEMM (batched over all t): hid = tanh(HC @ Wd1^T + b) -> bf16 ----------------
__global__ __launch_bounds__(256) void k_gemm_d1(const __bf16* __restrict__ A,
                                                 const __bf16* __restrict__ Bt,
                                                 const float* __restrict__ bias,
                                                 __bf16* __restrict__ C,
                                                 int M, int N, int K) {
    __shared__ __align__(16) char smem[16384];
    __bf16* Als = (__bf16*)smem;            // [128][32]
    __bf16* Bls = (__bf16*)(smem + 8192);   // [128][32]
    const int tid = threadIdx.x, lane = tid & 63, wave = tid >> 6;
    const int wm = wave >> 1, wn = wave & 1;
    const int bm = blockIdx.y * 128, bn = blockIdx.x * 128;
    const int srow = wave * 16 + (lane >> 2);
    const int scol = (lane & 3) * 8;
    const int fr = lane & 15, fq = lane >> 4;

    f32x4 acc[4][4];
#pragma unroll
    for (int i = 0; i < 4; ++i)
#pragma unroll
        for (int j = 0; j < 4; ++j) acc[i][j] = (f32x4){0.f,0.f,0.f,0.f};

    const int nkt = K >> 5;
    for (int kt = 0; kt < nkt; ++kt) {
        const int k0 = kt << 5;
        GL(A  + (size_t)(bm + srow) * K + k0 + scol,      smem + wave * 1024);
        GL(A  + (size_t)(bm + 64 + srow) * K + k0 + scol, smem + 4096 + wave * 1024);
        GL(Bt + (size_t)(bn + srow) * K + k0 + scol,      smem + 8192 + wave * 1024);
        GL(Bt + (size_t)(bn + 64 + srow) * K + k0 + scol, smem + 12288 + wave * 1024);
        __syncthreads();
        bf16x8 af[4], bfr[4];
#pragma unroll
        for (int mi = 0; mi < 4; ++mi)
            af[mi] = *(const bf16x8*)(Als + (wm*64 + mi*16 + fr) * 32 + fq * 8);
#pragma unroll
        for (int ni = 0; ni < 4; ++ni)
            bfr[ni] = *(const bf16x8*)(Bls + (wn*64 + ni*16 + fr) * 32 + fq * 8);
#pragma unroll
        for (int mi = 0; mi < 4; ++mi)
#pragma unroll
            for (int ni = 0; ni < 4; ++ni)
                acc[mi][ni] = __builtin_amdgcn_mfma_f32_16x16x32_bf16(af[mi], bfr[ni], acc[mi][ni], 0, 0, 0);
        __syncthreads();
    }
    const int cr = fq * 4, cc = fr;
#pragma unroll
    for (int ni = 0; ni < 4; ++ni) {
        const int gc = bn + wn*64 + ni*16 + cc;
        const float bv = bias[gc];
#pragma unroll
        for (int mi = 0; mi < 4; ++mi) {
            const int gr = bm + wm*64 + mi*16 + cr;
#pragma unroll
            for (int r = 0; r < 4; ++r)
                C[(size_t)(gr + r) * N + gc] = f2bf(tanhf(acc[mi][ni][r] + bv));
        }
    }
}

// ---------------- big GEMM: C[M,N] = A[M,K] * Bt[N,K]^T + bias ----------------
__global__ __launch_bounds__(256) void k_gemm_bt(const __bf16* __restrict__ A,
                                                 const __bf16* __restrict__ Bt,
                                                 const float* __restrict__ bias,
                                                 float* __restrict__ C,
                                                 int M, int N, int K) {
    __shared__ __align__(16) char smem[16384];
    __bf16* Als = (__bf16*)smem;            // [128][32]
    __bf16* Bls = (__bf16*)(smem + 8192);   // [128][32]
    const int tid = threadIdx.x, lane = tid & 63, wave = tid >> 6;
    const int wm = wave >> 1, wn = wave & 1;
    const int bm = blockIdx.y * 128, bn = blockIdx.x * 128;
    const int srow = wave * 16 + (lane >> 2);
    const int scol = (lane & 3) * 8;
    const int fr = lane & 15, fq = lane >> 4;

    f32x4 acc[4][4];
#pragma unroll
    for (int i = 0; i < 4; ++i)
#pragma unroll
        for (int j = 0; j < 4; ++j) acc[i][j] = (f32x4){0.f,0.f,0.f,0.f};

    const int nkt = K >> 5;
    for (int kt = 0; kt < nkt; ++kt) {
        const int k0 = kt << 5;
        GL(A  + (size_t)(bm + srow) * K + k0 + scol,      smem + wave * 1024);
        GL(A  + (size_t)(bm + 64 + srow) * K + k0 + scol, smem + 4096 + wave * 1024);
        GL(Bt + (size_t)(bn + srow) * K + k0 + scol,      smem + 8192 + wave * 1024);
        GL(Bt + (size_t)(bn + 64 + srow) * K + k0 + scol, smem + 12288 + wave * 1024);
        __syncthreads();
        bf16x8 af[4], bfr[4];
#pragma unroll
        for (int mi = 0; mi < 4; ++mi)
            af[mi] = *(const bf16x8*)(Als + (wm*64 + mi*16 + fr) * 32 + fq * 8);
#pragma unroll
        for (int ni = 0; ni < 4; ++ni)
            bfr[ni] = *(const bf16x8*)(Bls + (wn*64 + ni*16 + fr) * 32 + fq * 8);
#pragma unroll
        for (int mi = 0; mi < 4; ++mi)
#pragma unroll
            for (int ni = 0; ni < 4; ++ni)
                acc[mi][ni] = __builtin_amdgcn_mfma_f32_16x16x32_bf16(af[mi], bfr[ni], acc[mi][ni], 0, 0, 0);
        __syncthreads();
    }
    const int cr = fq * 4, cc = fr;
#pragma unroll
    for (int ni = 0; ni < 4; ++ni) {
        const int gc = bn + wn*64 + ni*16 + cc;
        const float bv = bias ? bias[gc] : 0.f;
#pragma unroll
        for (int mi = 0; mi < 4; ++mi) {
            const int gr = bm + wm*64 + mi*16 + cr;
            float* cp = C + (size_t)gr * N + gc;
#pragma unroll
            for (int r = 0; r < 4; ++r) cp[(size_t)r * N] = acc[mi][ni][r] + bv;
        }
    }
}

extern "C" void kernel_launch(void* const* d_in, const int* in_sizes, int n_in,
                              void* d_out, int out_size, void* d_ws, size_t ws_size,
                              hipStream_t stream) {
    const int*   seq     = (const int*)d_in[0];
    const float* ctx     = (const float*)d_in[1];
    const float* emb     = (const float*)d_in[2];
    const float* W_ih    = (const float*)d_in[3];
    const float* b_ih    = (const float*)d_in[4];
    const float* W_hh    = (const float*)d_in[5];
    const float* b_hh    = (const float*)d_in[6];
    const float* W_initS = (const float*)d_in[7];
    const float* b_initS = (const float*)d_in[8];
    const float* W_initC = (const float*)d_in[9];
    const float* b_initC = (const float*)d_in[10];
    const float* W_d1    = (const float*)d_in[11];
    const float* b_d1    = (const float*)d_in[12];
    const float* W_d2    = (const float*)d_in[13];
    const float* b_d2    = (const float*)d_in[14];
    float* out = (float*)d_out;

    // workspace layout (~100 MiB)
    char* ws = (char*)d_ws;
    __bf16* Whh_bf  = (__bf16*)(ws + 0);                    //  8 MiB (reused as hid later)
    __bf16* WihE_bf = (__bf16*)(ws + (8u << 20));           //  4 MiB
    __bf16* Wd1_bf  = (__bf16*)(ws + (12u << 20));          //  4 MiB
    __bf16* Wd2_bf  = (__bf16*)(ws + (16u << 20));          //  62.5 MiB
    __bf16* X_bf    = (__bf16*)(ws + 82313216u);            //  4 MiB
    float*  ctxg    = (float*) (ws + 86507520u);            //  1 MiB
    __bf16* hbuf0   = (__bf16*)(ws + 87556096u);            //  128 KiB
    __bf16* hbuf1   = (__bf16*)(ws + 87687168u);            //  128 KiB
    float*  cbuf    = (float*) (ws + 87818240u);            //  256 KiB
    __bf16* HCall   = (__bf16*)(ws + 88080384u);            //  16 MiB  [T][B][2H]
    unsigned* bar   = (unsigned*)(ws + 104857600u);         //  4 KiB barrier counters
    __bf16* hid     = (__bf16*)(ws + 0);                    //  aliases Whh_bf (dead after k_rnn)

    // one-time precompute
    k_cast<<<4096, 256, 0, stream>>>(W_hh, Whh_bf, 1048576);
    k_cast_wihe<<<2048, 256, 0, stream>>>(W_ih, WihE_bf);
    k_cast<<<2048, 256, 0, stream>>>(W_d1, Wd1_bf, 524288);
    k_cast<<<32000, 256, 0, stream>>>(W_d2, Wd2_bf, 8192000);
    k_gather_x<<<2048, 256, 0, stream>>>(seq, emb, X_bf);
    k_init<<<128, 256, 0, stream>>>(ctx, W_initS, b_initS, W_initC, b_initC, hbuf0, cbuf);
    k_ctxgates<<<256, 256, 0, stream>>>(ctx, W_ih, b_ih, b_hh, ctxg);
    k_zero<<<1, 1024, 0, stream>>>(bar);

    // whole recurrence in ONE persistent kernel (weights + c-state in registers)
    k_rnn<<<NRB, 512, 0, stream>>>(Whh_bf, WihE_bf, X_bf, ctxg, cbuf,
                                   hbuf0, hbuf1, HCall, bar);

    // batched d1: hid[T*B, H] = tanh(HC[T*B, 2H] @ W_d1^T + b_d1)
    k_gemm_d1<<<dim3(H_ / 128, (T_ * B_) / 128), 256, 0, stream>>>(
        HCall, Wd1_bf, b_d1, hid, T_ * B_, H_, 2 * H_);

    // out[T*B, V] = hid @ W_d2^T + b_d2
    k_gemm_bt<<<dim3(V_ / 128, (T_ * B_) / 128), 256, 0, stream>>>(
        hid, Wd2_bf, b_d2, out, T_ * B_, V_, H_);
}

// Round 2
// 2165.039 us; speedup vs baseline: 1.5566x; 1.4278x over previous
//
#include <hip/hip_runtime.h>
#include <hip/hip_bf16.h>
#include <cstdint>

// Problem constants
#define V_  32000
#define E_  512
#define H_  1024
#define CTX_ 1024
#define T_  64
#define B_  64
#define FH_ 4096   // 4*H
#define NRB 128    // persistent recurrence blocks (<= 256 CUs -> co-resident)

typedef __attribute__((ext_vector_type(8))) __bf16 bf16x8;
typedef __attribute__((ext_vector_type(4))) __bf16 bf16x4;
typedef __attribute__((ext_vector_type(4))) float f32x4;

#define DEV static __device__ __forceinline__

DEV __bf16 f2bf(float f) {
    union { float f; unsigned u; } v; v.f = f;
    unsigned r = (v.u + 0x7FFFu + ((v.u >> 16) & 1u)) >> 16;
    unsigned short s = (unsigned short)r;
    return __builtin_bit_cast(__bf16, s);
}

DEV float sigm(float x) { return 1.0f / (1.0f + __expf(-x)); }

// coherent (agent-scope, sc1 -> bypasses per-XCD L2, hits LLC) 8B load/store
DEV unsigned long long ld8cc(const __bf16* p) {
    return __hip_atomic_load((const unsigned long long*)p,
                             __ATOMIC_RELAXED, __HIP_MEMORY_SCOPE_AGENT);
}
DEV void st8cc(__bf16* p, unsigned long long v) {
    __hip_atomic_store((unsigned long long*)p, v,
                       __ATOMIC_RELAXED, __HIP_MEMORY_SCOPE_AGENT);
}

// async global->LDS, 16B per lane; LDS dest = wave-uniform base + lane*16
#define GL(g, l) __builtin_amdgcn_global_load_lds(                         \
    (const __attribute__((address_space(1))) void*)(g),                    \
    (__attribute__((address_space(3))) void*)(l), 16, 0, 0)

// ---------------- casts / gathers ----------------
__global__ __launch_bounds__(256) void k_cast(const float* __restrict__ src,
                                              __bf16* __restrict__ dst, int n4) {
    int i = blockIdx.x * 256 + threadIdx.x;
    if (i >= n4) return;
    float4 v = *(const float4*)(src + (size_t)i * 4);
    bf16x4 o; o[0]=f2bf(v.x); o[1]=f2bf(v.y); o[2]=f2bf(v.z); o[3]=f2bf(v.w);
    *(bf16x4*)(dst + (size_t)i * 4) = o;
}

// W_ihE = bf16(W_ih[:, CTX:CTX+E])  -> [4096][512]
__global__ __launch_bounds__(256) void k_cast_wihe(const float* __restrict__ Wih,
                                                   __bf16* __restrict__ dst) {
    int i = blockIdx.x * 256 + threadIdx.x;   // 524288 threads, 4 elems each
    int e = i * 4, j = e >> 9, k = e & 511;
    float4 v = *(const float4*)(Wih + (size_t)j * (CTX_ + E_) + CTX_ + k);
    bf16x4 o; o[0]=f2bf(v.x); o[1]=f2bf(v.y); o[2]=f2bf(v.z); o[3]=f2bf(v.w);
    *(bf16x4*)(dst + (size_t)e) = o;
}

// X[t*64+b][k] = bf16(emb[seq[t*64+b]][k])  -> [4096][512]
__global__ __launch_bounds__(256) void k_gather_x(const int* __restrict__ seq,
                                                  const float* __restrict__ emb,
                                                  __bf16* __restrict__ dst) {
    int i = blockIdx.x * 256 + threadIdx.x;
    int e = i * 4, r = e >> 9, k = e & 511;
    int tok = seq[r];
    float4 v = *(const float4*)(emb + (size_t)tok * E_ + k);
    bf16x4 o; o[0]=f2bf(v.x); o[1]=f2bf(v.y); o[2]=f2bf(v.z); o[3]=f2bf(v.w);
    *(bf16x4*)(dst + (size_t)e) = o;
}

// ---------------- init state: h0 -> HCx[0] h-part (stride 2048), c0 (f32) ----------------
__global__ __launch_bounds__(256) void k_init(const float* __restrict__ ctx,
                                              const float* __restrict__ WS, const float* __restrict__ bS,
                                              const float* __restrict__ WC, const float* __restrict__ bC,
                                              __bf16* __restrict__ h0, float* __restrict__ c0) {
    int idx = blockIdx.x * 256 + threadIdx.x;   // 32768
    int r = idx >> 4, bg = idx & 15;
    int sel = r >> 10, u = r & 1023;
    const float4* w = (const float4*)((sel ? WC : WS) + (size_t)u * CTX_);
    float acc[4] = {0.f,0.f,0.f,0.f};
    for (int k = 0; k < 256; ++k) {
        float4 wv = w[k];
#pragma unroll
        for (int i = 0; i < 4; ++i) {
            float4 cv = *(const float4*)(ctx + (size_t)(bg + 16*i) * CTX_ + k * 4);
            acc[i] += wv.x*cv.x + wv.y*cv.y + wv.z*cv.z + wv.w*cv.w;
        }
    }
    float bias = sel ? bC[u] : bS[u];
#pragma unroll
    for (int i = 0; i < 4; ++i) {
        int b = bg + 16*i;
        float v = tanhf(acc[i] + bias);
        if (sel) c0[(size_t)b * H_ + u] = v;
        else     h0[(size_t)b * 2048 + u] = f2bf(v);   // into HCx[0][b][u]
    }
}

// ---------------- ctx_gates[b][j] = ctx[b]·W_ih[j][0:CTX] + b_ih[j] + b_hh[j] ----------------
__global__ __launch_bounds__(256) void k_ctxgates(const float* __restrict__ ctx,
                                                  const float* __restrict__ Wih,
                                                  const float* __restrict__ bih,
                                                  const float* __restrict__ bhh,
                                                  float* __restrict__ out) {
    int idx = blockIdx.x * 256 + threadIdx.x;   // 65536
    int j = idx >> 4, bg = idx & 15;
    const float4* w = (const float4*)(Wih + (size_t)j * (CTX_ + E_));
    float acc[4] = {0.f,0.f,0.f,0.f};
    for (int k = 0; k < 256; ++k) {
        float4 wv = w[k];
#pragma unroll
        for (int i = 0; i < 4; ++i) {
            float4 cv = *(const float4*)(ctx + (size_t)(bg + 16*i) * CTX_ + k * 4);
            acc[i] += wv.x*cv.x + wv.y*cv.y + wv.z*cv.z + wv.w*cv.w;
        }
    }
    float bias = bih[j] + bhh[j];
#pragma unroll
    for (int i = 0; i < 4; ++i) out[(size_t)(bg + 16*i) * FH_ + j] = acc[i] + bias;
}

// ---------------- barrier state zero ----------------
__global__ __launch_bounds__(1024) void k_zero(unsigned* __restrict__ bar) {
    bar[threadIdx.x] = 0u;
}

// ---------------- persistent recurrence kernel ----------------
// 128 blocks x 512 threads. Block owns u in [blockIdx*8, blockIdx*8+8)
// (32 gate columns: 4 gates x 8 units). Weights live in registers.
// State buffer HCx = [T+1][B][2H] bf16; step t reads slot t (h-part), writes slot t+1.
// ALL cross-step traffic uses sc1 (agent-coherent) loads/stores -> no L2
// inv/wb anywhere in the loop; barrier is relaxed add + relaxed spin.
__global__ __launch_bounds__(512, 2) void k_rnn(
    const __bf16* __restrict__ Whh, const __bf16* __restrict__ WihE,
    const __bf16* __restrict__ Xb, const float* __restrict__ ctxg,
    const float* __restrict__ c0,
    __bf16* __restrict__ HCx, unsigned* __restrict__ bar)
{
    __shared__ float red[8][64][36];   // partial-sum exchange (2-way bank alias = free)
    __shared__ __bf16 hnb[64][8];      // repack buffers for coalesced 8B coherent stores
    __shared__ __bf16 cnb[64][8];
    const int tid = threadIdx.x;
    const int w = tid >> 6, lane = tid & 63;
    const int fr = lane & 15, fq = lane >> 4;
    const int u0 = (int)blockIdx.x * 8;
    const int kb = w * 192;            // this wave's K-slice base (of 1536)

    // ---- one-time: B fragments into registers (48 VGPRs) ----
    bf16x8 breg[2][6];
#pragma unroll
    for (int ni = 0; ni < 2; ++ni) {
        const int n = ni * 16 + fr;                       // output col 0..31
        const int j = (n >> 3) * H_ + u0 + (n & 7);       // gate row in [0,4096)
#pragma unroll
        for (int ks = 0; ks < 6; ++ks) {
            const int k = kb + ks * 32;
            const __bf16* src = (k < H_) ? (Whh + (size_t)j * H_ + k)
                                         : (WihE + (size_t)j * E_ + (k - H_));
            breg[ni][ks] = *(const bf16x8*)(src + fq * 8);
        }
    }
    // ---- one-time: cell state + ctx-gate biases into registers ----
    const int cb = tid >> 3, cul = tid & 7, u = u0 + cul;
    float creg = c0[(size_t)cb * H_ + u];
    float cg[4];
#pragma unroll
    for (int g = 0; g < 4; ++g) cg[g] = ctxg[(size_t)cb * FH_ + g * H_ + u];

#pragma unroll 1
    for (int t = 0; t < T_; ++t) {
        const __bf16* hprev = HCx + (size_t)t * (B_ * 2 * H_);
        __bf16*       hcur  = HCx + (size_t)(t + 1) * (B_ * 2 * H_);
        const __bf16* Xt = Xb + (size_t)t * (B_ * E_);

        f32x4 acc[4][2];
#pragma unroll
        for (int mi = 0; mi < 4; ++mi)
#pragma unroll
            for (int ni = 0; ni < 2; ++ni) acc[mi][ni] = (f32x4){0.f,0.f,0.f,0.f};

        // partial GEMM over this wave's K-slice; h via coherent LLC loads, X via L2
#pragma unroll
        for (int ks = 0; ks < 6; ++ks) {
            const int k = kb + ks * 32;
            bf16x8 af[4];
            if (k < H_) {
#pragma unroll
                for (int mi = 0; mi < 4; ++mi) {
                    const __bf16* s = hprev + (size_t)(mi * 16 + fr) * 2048 + k + fq * 8;
                    union { unsigned long long q[2]; bf16x8 v; } uu;
                    uu.q[0] = ld8cc(s); uu.q[1] = ld8cc(s + 4);
                    af[mi] = uu.v;
                }
            } else {
#pragma unroll
                for (int mi = 0; mi < 4; ++mi)
                    af[mi] = *(const bf16x8*)(Xt + (size_t)(mi * 16 + fr) * E_ + (k - H_) + fq * 8);
            }
#pragma unroll
            for (int mi = 0; mi < 4; ++mi)
#pragma unroll
                for (int ni = 0; ni < 2; ++ni)
                    acc[mi][ni] = __builtin_amdgcn_mfma_f32_16x16x32_bf16(
                        af[mi], breg[ni][ks], acc[mi][ni], 0, 0, 0);
        }
        // partials -> LDS  (C/D frag: col=lane&15, row=fq*4+r)
#pragma unroll
        for (int mi = 0; mi < 4; ++mi)
#pragma unroll
            for (int ni = 0; ni < 2; ++ni)
#pragma unroll
                for (int r = 0; r < 4; ++r)
                    red[w][mi * 16 + fq * 4 + r][ni * 16 + fr] = acc[mi][ni][r];
        __syncthreads();

        // 8-way reduce + fused cell update; thread owns (cb, cul)
        float gv[4];
#pragma unroll
        for (int g = 0; g < 4; ++g) {
            float s = cg[g];
#pragma unroll
            for (int wv = 0; wv < 8; ++wv) s += red[wv][cb][g * 8 + cul];
            gv[g] = s;
        }
        const float cn = sigm(gv[1]) * creg + sigm(gv[0]) * tanhf(gv[2]);
        const float hn = sigm(gv[3]) * tanhf(cn);
        creg = cn;
        hnb[cb][cul] = f2bf(hn);
        cnb[cb][cul] = f2bf(cn);
        __syncthreads();

        // coalesced coherent stores: 256 x 8B covers [64 rows][8 units] x {h,c}
        if (tid < 256) {
            const int b = tid >> 2, sel = (tid >> 1) & 1, hf = tid & 1;
            const __bf16* s = sel ? &cnb[b][hf * 4] : &hnb[b][hf * 4];
            unsigned long long q = *(const unsigned long long*)s;
            st8cc(hcur + (size_t)b * 2048 + sel * H_ + u0 + hf * 4, q);
        }

        // ---- grid barrier: syncthreads drains vmcnt (sc1 stores at LLC),
        //      then relaxed add + relaxed spin. No cache maintenance. ----
        __syncthreads();
        if (tid == 0) {
            unsigned* b4 = bar + t * 16;   // 64B-strided counters
            __hip_atomic_fetch_add(b4, 1u, __ATOMIC_RELAXED, __HIP_MEMORY_SCOPE_AGENT);
            while (__hip_atomic_load(b4, __ATOMIC_RELAXED, __HIP_MEMORY_SCOPE_AGENT)
                   < (unsigned)NRB) { }
        }
        __syncthreads();
    }
}

// ---------------- d1 GEMM (batched over all t): hid = tanh(HC @ Wd1^T + b) -> bf16 ----------------
__global__ __launch_bounds__(256) void k_gemm_d1(const __bf16* __restrict__ A,
                                                 const __bf16* __restrict__ Bt,
                                                 const float* __restrict__ bias,
                                                 __bf16* __restrict__ C,
                                                 int M, int N, int K) {
    __shared__ __align__(16) char smem[16384];
    __bf16* Als = (__bf16*)smem;            // [128][32]
    __bf16* Bls = (__bf16*)(smem + 8192);   // [128][32]
    const int tid = threadIdx.x, lane = tid & 63, wave = tid >> 6;
    const int wm = wave >> 1, wn = wave & 1;
    const int bm = blockIdx.y * 128, bn = blockIdx.x * 128;
    const int srow = wave * 16 + (lane >> 2);
    const int scol = (lane & 3) * 8;
    const int fr = lane & 15, fq = lane >> 4;

    f32x4 acc[4][4];
#pragma unroll
    for (int i = 0; i < 4; ++i)
#pragma unroll
        for (int j = 0; j < 4; ++j) acc[i][j] = (f32x4){0.f,0.f,0.f,0.f};

    const int nkt = K >> 5;
    for (int kt = 0; kt < nkt; ++kt) {
        const int k0 = kt << 5;
        GL(A  + (size_t)(bm + srow) * K + k0 + scol,      smem + wave * 1024);
        GL(A  + (size_t)(bm + 64 + srow) * K + k0 + scol, smem + 4096 + wave * 1024);
        GL(Bt + (size_t)(bn + srow) * K + k0 + scol,      smem + 8192 + wave * 1024);
        GL(Bt + (size_t)(bn + 64 + srow) * K + k0 + scol, smem + 12288 + wave * 1024);
        __syncthreads();
        bf16x8 af[4], bfr[4];
#pragma unroll
        for (int mi = 0; mi < 4; ++mi)
            af[mi] = *(const bf16x8*)(Als + (wm*64 + mi*16 + fr) * 32 + fq * 8);
#pragma unroll
        for (int ni = 0; ni < 4; ++ni)
            bfr[ni] = *(const bf16x8*)(Bls + (wn*64 + ni*16 + fr) * 32 + fq * 8);
#pragma unroll
        for (int mi = 0; mi < 4; ++mi)
#pragma unroll
            for (int ni = 0; ni < 4; ++ni)
                acc[mi][ni] = __builtin_amdgcn_mfma_f32_16x16x32_bf16(af[mi], bfr[ni], acc[mi][ni], 0, 0, 0);
        __syncthreads();
    }
    const int cr = fq * 4, cc = fr;
#pragma unroll
    for (int ni = 0; ni < 4; ++ni) {
        const int gc = bn + wn*64 + ni*16 + cc;
        const float bv = bias[gc];
#pragma unroll
        for (int mi = 0; mi < 4; ++mi) {
            const int gr = bm + wm*64 + mi*16 + cr;
#pragma unroll
            for (int r = 0; r < 4; ++r)
                C[(size_t)(gr + r) * N + gc] = f2bf(tanhf(acc[mi][ni][r] + bv));
        }
    }
}

// ---------------- big GEMM: C[M,N] = A[M,K] * Bt[N,K]^T + bias ----------------
__global__ __launch_bounds__(256) void k_gemm_bt(const __bf16* __restrict__ A,
                                                 const __bf16* __restrict__ Bt,
                                                 const float* __restrict__ bias,
                                                 float* __restrict__ C,
                                                 int M, int N, int K) {
    __shared__ __align__(16) char smem[16384];
    __bf16* Als = (__bf16*)smem;            // [128][32]
    __bf16* Bls = (__bf16*)(smem + 8192);   // [128][32]
    const int tid = threadIdx.x, lane = tid & 63, wave = tid >> 6;
    const int wm = wave >> 1, wn = wave & 1;
    const int bm = blockIdx.y * 128, bn = blockIdx.x * 128;
    const int srow = wave * 16 + (lane >> 2);
    const int scol = (lane & 3) * 8;
    const int fr = lane & 15, fq = lane >> 4;

    f32x4 acc[4][4];
#pragma unroll
    for (int i = 0; i < 4; ++i)
#pragma unroll
        for (int j = 0; j < 4; ++j) acc[i][j] = (f32x4){0.f,0.f,0.f,0.f};

    const int nkt = K >> 5;
    for (int kt = 0; kt < nkt; ++kt) {
        const int k0 = kt << 5;
        GL(A  + (size_t)(bm + srow) * K + k0 + scol,      smem + wave * 1024);
        GL(A  + (size_t)(bm + 64 + srow) * K + k0 + scol, smem + 4096 + wave * 1024);
        GL(Bt + (size_t)(bn + srow) * K + k0 + scol,      smem + 8192 + wave * 1024);
        GL(Bt + (size_t)(bn + 64 + srow) * K + k0 + scol, smem + 12288 + wave * 1024);
        __syncthreads();
        bf16x8 af[4], bfr[4];
#pragma unroll
        for (int mi = 0; mi < 4; ++mi)
            af[mi] = *(const bf16x8*)(Als + (wm*64 + mi*16 + fr) * 32 + fq * 8);
#pragma unroll
        for (int ni = 0; ni < 4; ++ni)
            bfr[ni] = *(const bf16x8*)(Bls + (wn*64 + ni*16 + fr) * 32 + fq * 8);
#pragma unroll
        for (int mi = 0; mi < 4; ++mi)
#pragma unroll
            for (int ni = 0; ni < 4; ++ni)
                acc[mi][ni] = __builtin_amdgcn_mfma_f32_16x16x32_bf16(af[mi], bfr[ni], acc[mi][ni], 0, 0, 0);
        __syncthreads();
    }
    const int cr = fq * 4, cc = fr;
#pragma unroll
    for (int ni = 0; ni < 4; ++ni) {
        const int gc = bn + wn*64 + ni*16 + cc;
        const float bv = bias ? bias[gc] : 0.f;
#pragma unroll
        for (int mi = 0; mi < 4; ++mi) {
            const int gr = bm + wm*64 + mi*16 + cr;
            float* cp = C + (size_t)gr * N + gc;
#pragma unroll
            for (int r = 0; r < 4; ++r) cp[(size_t)r * N] = acc[mi][ni][r] + bv;
        }
    }
}

extern "C" void kernel_launch(void* const* d_in, const int* in_sizes, int n_in,
                              void* d_out, int out_size, void* d_ws, size_t ws_size,
                              hipStream_t stream) {
    const int*   seq     = (const int*)d_in[0];
    const float* ctx     = (const float*)d_in[1];
    const float* emb     = (const float*)d_in[2];
    const float* W_ih    = (const float*)d_in[3];
    const float* b_ih    = (const float*)d_in[4];
    const float* W_hh    = (const float*)d_in[5];
    const float* b_hh    = (const float*)d_in[6];
    const float* W_initS = (const float*)d_in[7];
    const float* b_initS = (const float*)d_in[8];
    const float* W_initC = (const float*)d_in[9];
    const float* b_initC = (const float*)d_in[10];
    const float* W_d1    = (const float*)d_in[11];
    const float* b_d1    = (const float*)d_in[12];
    const float* W_d2    = (const float*)d_in[13];
    const float* b_d2    = (const float*)d_in[14];
    float* out = (float*)d_out;

    // workspace layout (~100 MiB)
    char* ws = (char*)d_ws;
    __bf16* Whh_bf  = (__bf16*)(ws + 0);                    //  8 MiB (reused as hid later)
    __bf16* WihE_bf = (__bf16*)(ws + (8u << 20));           //  4 MiB
    __bf16* Wd1_bf  = (__bf16*)(ws + (12u << 20));          //  4 MiB
    __bf16* Wd2_bf  = (__bf16*)(ws + (16u << 20));          //  62.5 MiB -> ends 82313216
    __bf16* X_bf    = (__bf16*)(ws + 82313216u);            //  4 MiB   -> 86507520
    float*  ctxg    = (float*) (ws + 86507520u);            //  1 MiB   -> 87556096
    float*  cbuf    = (float*) (ws + 87556096u);            //  256 KiB -> 87818240
    __bf16* HCx     = (__bf16*)(ws + 87818240u);            //  [65][64][2048] bf16 = 17039360 -> 104857600
    unsigned* bar   = (unsigned*)(ws + 104857600u);         //  4 KiB barrier counters
    __bf16* hid     = (__bf16*)(ws + 0);                    //  aliases Whh_bf (dead after k_rnn)

    // one-time precompute
    k_cast<<<4096, 256, 0, stream>>>(W_hh, Whh_bf, 1048576);
    k_cast_wihe<<<2048, 256, 0, stream>>>(W_ih, WihE_bf);
    k_cast<<<2048, 256, 0, stream>>>(W_d1, Wd1_bf, 524288);
    k_cast<<<32000, 256, 0, stream>>>(W_d2, Wd2_bf, 8192000);
    k_gather_x<<<2048, 256, 0, stream>>>(seq, emb, X_bf);
    k_init<<<128, 256, 0, stream>>>(ctx, W_initS, b_initS, W_initC, b_initC, HCx, cbuf);
    k_ctxgates<<<256, 256, 0, stream>>>(ctx, W_ih, b_ih, b_hh, ctxg);
    k_zero<<<1, 1024, 0, stream>>>(bar);

    // whole recurrence in ONE persistent kernel (weights + c-state in registers)
    k_rnn<<<NRB, 512, 0, stream>>>(Whh_bf, WihE_bf, X_bf, ctxg, cbuf, HCx, bar);

    // batched d1: hid[T*B, H] = tanh(HC[T*B, 2H] @ W_d1^T + b_d1); skip HCx slot 0
    k_gemm_d1<<<dim3(H_ / 128, (T_ * B_) / 128), 256, 0, stream>>>(
        HCx + (size_t)B_ * 2 * H_, Wd1_bf, b_d1, hid, T_ * B_, H_, 2 * H_);

    // out[T*B, V] = hid @ W_d2^T + b_d2
    k_gemm_bt<<<dim3(V_ / 128, (T_ * B_) / 128), 256, 0, stream>>>(
        hid, Wd2_bf, b_d2, out, T_ * B_, V_, H_);
}

// Round 3
// 2013.292 us; speedup vs baseline: 1.6739x; 1.0754x over previous
//
#include <hip/hip_runtime.h>
#include <hip/hip_bf16.h>
#include <cstdint>

// Problem constants
#define V_  32000
#define E_  512
#define H_  1024
#define CTX_ 1024
#define T_  64
#define B_  64
#define FH_ 4096   // 4*H
#define NRB 128    // persistent recurrence blocks (<= 256 CUs -> co-resident)

typedef __attribute__((ext_vector_type(8))) __bf16 bf16x8;
typedef __attribute__((ext_vector_type(4))) __bf16 bf16x4;
typedef __attribute__((ext_vector_type(4))) float f32x4;

#define DEV static __device__ __forceinline__

DEV __bf16 f2bf(float f) {
    union { float f; unsigned u; } v; v.f = f;
    unsigned r = (v.u + 0x7FFFu + ((v.u >> 16) & 1u)) >> 16;
    unsigned short s = (unsigned short)r;
    return __builtin_bit_cast(__bf16, s);
}

DEV float sigm(float x) { return 1.0f / (1.0f + __expf(-x)); }

// coherent (agent-scope, sc1 -> write-through to LLC) 8B store
DEV void st8cc(__bf16* p, unsigned long long v) {
    __hip_atomic_store((unsigned long long*)p, v,
                       __ATOMIC_RELAXED, __HIP_MEMORY_SCOPE_AGENT);
}

// async global->LDS, 16B per lane; LDS dest = wave-uniform base + lane*16
#define GL(g, l) __builtin_amdgcn_global_load_lds(                         \
    (const __attribute__((address_space(1))) void*)(g),                    \
    (__attribute__((address_space(3))) void*)(l), 16, 0, 0)

// ---------------- casts / gathers ----------------
__global__ __launch_bounds__(256) void k_cast(const float* __restrict__ src,
                                              __bf16* __restrict__ dst, int n4) {
    int i = blockIdx.x * 256 + threadIdx.x;
    if (i >= n4) return;
    float4 v = *(const float4*)(src + (size_t)i * 4);
    bf16x4 o; o[0]=f2bf(v.x); o[1]=f2bf(v.y); o[2]=f2bf(v.z); o[3]=f2bf(v.w);
    *(bf16x4*)(dst + (size_t)i * 4) = o;
}

// W_ihE = bf16(W_ih[:, CTX:CTX+E])  -> [4096][512]
__global__ __launch_bounds__(256) void k_cast_wihe(const float* __restrict__ Wih,
                                                   __bf16* __restrict__ dst) {
    int i = blockIdx.x * 256 + threadIdx.x;   // 524288 threads, 4 elems each
    int e = i * 4, j = e >> 9, k = e & 511;
    float4 v = *(const float4*)(Wih + (size_t)j * (CTX_ + E_) + CTX_ + k);
    bf16x4 o; o[0]=f2bf(v.x); o[1]=f2bf(v.y); o[2]=f2bf(v.z); o[3]=f2bf(v.w);
    *(bf16x4*)(dst + (size_t)e) = o;
}

// X[t*64+b][k] = bf16(emb[seq[t*64+b]][k])  -> [4096][512]
__global__ __launch_bounds__(256) void k_gather_x(const int* __restrict__ seq,
                                                  const float* __restrict__ emb,
                                                  __bf16* __restrict__ dst) {
    int i = blockIdx.x * 256 + threadIdx.x;
    int e = i * 4, r = e >> 9, k = e & 511;
    int tok = seq[r];
    float4 v = *(const float4*)(emb + (size_t)tok * E_ + k);
    bf16x4 o; o[0]=f2bf(v.x); o[1]=f2bf(v.y); o[2]=f2bf(v.z); o[3]=f2bf(v.w);
    *(bf16x4*)(dst + (size_t)e) = o;
}

// ---------------- init state: h0 -> HCx[0] h-part (stride 2048), c0 (f32) ----------------
__global__ __launch_bounds__(256) void k_init(const float* __restrict__ ctx,
                                              const float* __restrict__ WS, const float* __restrict__ bS,
                                              const float* __restrict__ WC, const float* __restrict__ bC,
                                              __bf16* __restrict__ h0, float* __restrict__ c0) {
    int idx = blockIdx.x * 256 + threadIdx.x;   // 32768
    int r = idx >> 4, bg = idx & 15;
    int sel = r >> 10, u = r & 1023;
    const float4* w = (const float4*)((sel ? WC : WS) + (size_t)u * CTX_);
    float acc[4] = {0.f,0.f,0.f,0.f};
    for (int k = 0; k < 256; ++k) {
        float4 wv = w[k];
#pragma unroll
        for (int i = 0; i < 4; ++i) {
            float4 cv = *(const float4*)(ctx + (size_t)(bg + 16*i) * CTX_ + k * 4);
            acc[i] += wv.x*cv.x + wv.y*cv.y + wv.z*cv.z + wv.w*cv.w;
        }
    }
    float bias = sel ? bC[u] : bS[u];
#pragma unroll
    for (int i = 0; i < 4; ++i) {
        int b = bg + 16*i;
        float v = tanhf(acc[i] + bias);
        if (sel) c0[(size_t)b * H_ + u] = v;
        else     h0[(size_t)b * 2048 + u] = f2bf(v);   // into HCx[0][b][u]
    }
}

// ---------------- ctx_gates[b][j] = ctx[b]·W_ih[j][0:CTX] + b_ih[j] + b_hh[j] ----------------
__global__ __launch_bounds__(256) void k_ctxgates(const float* __restrict__ ctx,
                                                  const float* __restrict__ Wih,
                                                  const float* __restrict__ bih,
                                                  const float* __restrict__ bhh,
                                                  float* __restrict__ out) {
    int idx = blockIdx.x * 256 + threadIdx.x;   // 65536
    int j = idx >> 4, bg = idx & 15;
    const float4* w = (const float4*)(Wih + (size_t)j * (CTX_ + E_));
    float acc[4] = {0.f,0.f,0.f,0.f};
    for (int k = 0; k < 256; ++k) {
        float4 wv = w[k];
#pragma unroll
        for (int i = 0; i < 4; ++i) {
            float4 cv = *(const float4*)(ctx + (size_t)(bg + 16*i) * CTX_ + k * 4);
            acc[i] += wv.x*cv.x + wv.y*cv.y + wv.z*cv.z + wv.w*cv.w;
        }
    }
    float bias = bih[j] + bhh[j];
#pragma unroll
    for (int i = 0; i < 4; ++i) out[(size_t)(bg + 16*i) * FH_ + j] = acc[i] + bias;
}

// ---------------- barrier state zero ----------------
__global__ __launch_bounds__(1024) void k_zero(unsigned* __restrict__ bar) {
    bar[threadIdx.x] = 0u;
}

// ---------------- persistent recurrence kernel ----------------
// 128 blocks x 512 threads. Block owns u in [blockIdx*8, blockIdx*8+8)
// (32 gate columns: 4 gates x 8 units). Weights live in registers.
// State buffer HCx = [T+1][B][2H] bf16; step t reads slot t (h-part), writes slot t+1.
// Coherence: STORES are sc1 write-through (data at LLC when vmcnt drains);
// LOADS are ordinary cached loads, made fresh by ONE agent-acquire fence
// (single buffer_inv) per step after barrier detection. 16 blocks/XCD then
// share h through L2 instead of each streaming it from LLC.
__global__ __launch_bounds__(512, 2) void k_rnn(
    const __bf16* __restrict__ Whh, const __bf16* __restrict__ WihE,
    const __bf16* __restrict__ Xb, const float* __restrict__ ctxg,
    const float* __restrict__ c0,
    __bf16* __restrict__ HCx, unsigned* __restrict__ bar)
{
    __shared__ float red[8][64][36];   // partial-sum exchange (2-way bank alias = free)
    __shared__ __bf16 hnb[64][8];      // repack buffers for coalesced 8B coherent stores
    __shared__ __bf16 cnb[64][8];
    const int tid = threadIdx.x;
    const int w = tid >> 6, lane = tid & 63;
    const int fr = lane & 15, fq = lane >> 4;
    const int u0 = (int)blockIdx.x * 8;
    const int kb = w * 192;            // this wave's K-slice base (of 1536)

    // ---- one-time: B fragments into registers (48 VGPRs) ----
    bf16x8 breg[2][6];
#pragma unroll
    for (int ni = 0; ni < 2; ++ni) {
        const int n = ni * 16 + fr;                       // output col 0..31
        const int j = (n >> 3) * H_ + u0 + (n & 7);       // gate row in [0,4096)
#pragma unroll
        for (int ks = 0; ks < 6; ++ks) {
            const int k = kb + ks * 32;
            const __bf16* src = (k < H_) ? (Whh + (size_t)j * H_ + k)
                                         : (WihE + (size_t)j * E_ + (k - H_));
            breg[ni][ks] = *(const bf16x8*)(src + fq * 8);
        }
    }
    // ---- one-time: cell state + ctx-gate biases into registers ----
    const int cb = tid >> 3, cul = tid & 7, u = u0 + cul;
    float creg = c0[(size_t)cb * H_ + u];
    float cg[4];
#pragma unroll
    for (int g = 0; g < 4; ++g) cg[g] = ctxg[(size_t)cb * FH_ + g * H_ + u];

#pragma unroll 1
    for (int t = 0; t < T_; ++t) {
        const __bf16* hprev = HCx + (size_t)t * (B_ * 2 * H_);
        __bf16*       hcur  = HCx + (size_t)(t + 1) * (B_ * 2 * H_);
        const __bf16* Xt = Xb + (size_t)t * (B_ * E_);

        f32x4 acc[4][2];
#pragma unroll
        for (int mi = 0; mi < 4; ++mi)
#pragma unroll
            for (int ni = 0; ni < 2; ++ni) acc[mi][ni] = (f32x4){0.f,0.f,0.f,0.f};

        // partial GEMM over this wave's K-slice; h via L2-cached loads
        // (fresh after the per-step acquire fence), X via L2
#pragma unroll
        for (int ks = 0; ks < 6; ++ks) {
            const int k = kb + ks * 32;
            bf16x8 af[4];
#pragma unroll
            for (int mi = 0; mi < 4; ++mi) {
                const int row = mi * 16 + fr;             // batch row
                const __bf16* src = (k < H_)
                    ? (hprev + (size_t)row * 2048 + k + fq * 8)
                    : (Xt + (size_t)row * E_ + (k - H_) + fq * 8);
                af[mi] = *(const bf16x8*)src;
            }
#pragma unroll
            for (int mi = 0; mi < 4; ++mi)
#pragma unroll
                for (int ni = 0; ni < 2; ++ni)
                    acc[mi][ni] = __builtin_amdgcn_mfma_f32_16x16x32_bf16(
                        af[mi], breg[ni][ks], acc[mi][ni], 0, 0, 0);
        }
        // partials -> LDS  (C/D frag: col=lane&15, row=fq*4+r)
#pragma unroll
        for (int mi = 0; mi < 4; ++mi)
#pragma unroll
            for (int ni = 0; ni < 2; ++ni)
#pragma unroll
                for (int r = 0; r < 4; ++r)
                    red[w][mi * 16 + fq * 4 + r][ni * 16 + fr] = acc[mi][ni][r];
        __syncthreads();

        // 8-way reduce + fused cell update; thread owns (cb, cul)
        float gv[4];
#pragma unroll
        for (int g = 0; g < 4; ++g) {
            float s = cg[g];
#pragma unroll
            for (int wv = 0; wv < 8; ++wv) s += red[wv][cb][g * 8 + cul];
            gv[g] = s;
        }
        const float cn = sigm(gv[1]) * creg + sigm(gv[0]) * tanhf(gv[2]);
        const float hn = sigm(gv[3]) * tanhf(cn);
        creg = cn;
        hnb[cb][cul] = f2bf(hn);
        cnb[cb][cul] = f2bf(cn);
        __syncthreads();

        // coalesced coherent stores: 256 x 8B covers [64 rows][8 units] x {h,c}
        if (tid < 256) {
            const int b = tid >> 2, sel = (tid >> 1) & 1, hf = tid & 1;
            const __bf16* s = sel ? &cnb[b][hf * 4] : &hnb[b][hf * 4];
            unsigned long long q = *(const unsigned long long*)s;
            st8cc(hcur + (size_t)b * 2048 + sel * H_ + u0 + hf * 4, q);
        }

        // ---- grid barrier: syncthreads drains vmcnt (sc1 stores at LLC),
        //      relaxed add + relaxed spin, then ONE acquire fence (buffer_inv)
        //      so the next step's ordinary h loads see fresh LLC data. ----
        __syncthreads();
        if (tid == 0) {
            unsigned* b4 = bar + t * 16;   // 64B-strided counters
            __hip_atomic_fetch_add(b4, 1u, __ATOMIC_RELAXED, __HIP_MEMORY_SCOPE_AGENT);
            while (__hip_atomic_load(b4, __ATOMIC_RELAXED, __HIP_MEMORY_SCOPE_AGENT)
                   < (unsigned)NRB) { }
            __builtin_amdgcn_fence(__ATOMIC_ACQUIRE, "agent");  // one buffer_inv/step
        }
        __syncthreads();
    }
}

// XCD-aware tile remap for 1D-grid GEMMs: xcd = bid%8 owns an M-chunk of
// (nty/8) row-tiles (A-chunk ~1MB stays in its L2); sweeps N with each
// B-tile reused by the chunk's row-tiles (yl innermost).
DEV void xcd_tiles(int bid, int ntx, int nty, int& x, int& y) {
    const int xcd = bid & 7, i = bid >> 3;
    const int cy = nty >> 3;            // row-tiles per XCD (nty % 8 == 0)
    x = i / cy;
    y = xcd * cy + (i % cy);
}

// ---------------- d1 GEMM (batched over all t): hid = tanh(HC @ Wd1^T + b) -> bf16 ----------------
__global__ __launch_bounds__(256) void k_gemm_d1(const __bf16* __restrict__ A,
                                                 const __bf16* __restrict__ Bt,
                                                 const float* __restrict__ bias,
                                                 __bf16* __restrict__ C,
                                                 int M, int N, int K) {
    __shared__ __align__(16) char smem[16384];
    __bf16* Als = (__bf16*)smem;            // [128][32]
    __bf16* Bls = (__bf16*)(smem + 8192);   // [128][32]
    const int tid = threadIdx.x, lane = tid & 63, wave = tid >> 6;
    const int wm = wave >> 1, wn = wave & 1;
    int tx, ty; xcd_tiles(blockIdx.x, N >> 7, M >> 7, tx, ty);
    const int bm = ty * 128, bn = tx * 128;
    const int srow = wave * 16 + (lane >> 2);
    const int scol = (lane & 3) * 8;
    const int fr = lane & 15, fq = lane >> 4;

    f32x4 acc[4][4];
#pragma unroll
    for (int i = 0; i < 4; ++i)
#pragma unroll
        for (int j = 0; j < 4; ++j) acc[i][j] = (f32x4){0.f,0.f,0.f,0.f};

    const int nkt = K >> 5;
    for (int kt = 0; kt < nkt; ++kt) {
        const int k0 = kt << 5;
        GL(A  + (size_t)(bm + srow) * K + k0 + scol,      smem + wave * 1024);
        GL(A  + (size_t)(bm + 64 + srow) * K + k0 + scol, smem + 4096 + wave * 1024);
        GL(Bt + (size_t)(bn + srow) * K + k0 + scol,      smem + 8192 + wave * 1024);
        GL(Bt + (size_t)(bn + 64 + srow) * K + k0 + scol, smem + 12288 + wave * 1024);
        __syncthreads();
        bf16x8 af[4], bfr[4];
#pragma unroll
        for (int mi = 0; mi < 4; ++mi)
            af[mi] = *(const bf16x8*)(Als + (wm*64 + mi*16 + fr) * 32 + fq * 8);
#pragma unroll
        for (int ni = 0; ni < 4; ++ni)
            bfr[ni] = *(const bf16x8*)(Bls + (wn*64 + ni*16 + fr) * 32 + fq * 8);
#pragma unroll
        for (int mi = 0; mi < 4; ++mi)
#pragma unroll
            for (int ni = 0; ni < 4; ++ni)
                acc[mi][ni] = __builtin_amdgcn_mfma_f32_16x16x32_bf16(af[mi], bfr[ni], acc[mi][ni], 0, 0, 0);
        __syncthreads();
    }
    const int cr = fq * 4, cc = fr;
#pragma unroll
    for (int ni = 0; ni < 4; ++ni) {
        const int gc = bn + wn*64 + ni*16 + cc;
        const float bv = bias[gc];
#pragma unroll
        for (int mi = 0; mi < 4; ++mi) {
            const int gr = bm + wm*64 + mi*16 + cr;
#pragma unroll
            for (int r = 0; r < 4; ++r)
                C[(size_t)(gr + r) * N + gc] = f2bf(tanhf(acc[mi][ni][r] + bv));
        }
    }
}

// ---------------- big GEMM: C[M,N] = A[M,K] * Bt[N,K]^T + bias ----------------
__global__ __launch_bounds__(256) void k_gemm_bt(const __bf16* __restrict__ A,
                                                 const __bf16* __restrict__ Bt,
                                                 const float* __restrict__ bias,
                                                 float* __restrict__ C,
                                                 int M, int N, int K) {
    __shared__ __align__(16) char smem[16384];
    __bf16* Als = (__bf16*)smem;            // [128][32]
    __bf16* Bls = (__bf16*)(smem + 8192);   // [128][32]
    const int tid = threadIdx.x, lane = tid & 63, wave = tid >> 6;
    const int wm = wave >> 1, wn = wave & 1;
    int tx, ty; xcd_tiles(blockIdx.x, N >> 7, M >> 7, tx, ty);
    const int bm = ty * 128, bn = tx * 128;
    const int srow = wave * 16 + (lane >> 2);
    const int scol = (lane & 3) * 8;
    const int fr = lane & 15, fq = lane >> 4;

    f32x4 acc[4][4];
#pragma unroll
    for (int i = 0; i < 4; ++i)
#pragma unroll
        for (int j = 0; j < 4; ++j) acc[i][j] = (f32x4){0.f,0.f,0.f,0.f};

    const int nkt = K >> 5;
    for (int kt = 0; kt < nkt; ++kt) {
        const int k0 = kt << 5;
        GL(A  + (size_t)(bm + srow) * K + k0 + scol,      smem + wave * 1024);
        GL(A  + (size_t)(bm + 64 + srow) * K + k0 + scol, smem + 4096 + wave * 1024);
        GL(Bt + (size_t)(bn + srow) * K + k0 + scol,      smem + 8192 + wave * 1024);
        GL(Bt + (size_t)(bn + 64 + srow) * K + k0 + scol, smem + 12288 + wave * 1024);
        __syncthreads();
        bf16x8 af[4], bfr[4];
#pragma unroll
        for (int mi = 0; mi < 4; ++mi)
            af[mi] = *(const bf16x8*)(Als + (wm*64 + mi*16 + fr) * 32 + fq * 8);
#pragma unroll
        for (int ni = 0; ni < 4; ++ni)
            bfr[ni] = *(const bf16x8*)(Bls + (wn*64 + ni*16 + fr) * 32 + fq * 8);
#pragma unroll
        for (int mi = 0; mi < 4; ++mi)
#pragma unroll
            for (int ni = 0; ni < 4; ++ni)
                acc[mi][ni] = __builtin_amdgcn_mfma_f32_16x16x32_bf16(af[mi], bfr[ni], acc[mi][ni], 0, 0, 0);
        __syncthreads();
    }
    const int cr = fq * 4, cc = fr;
#pragma unroll
    for (int ni = 0; ni < 4; ++ni) {
        const int gc = bn + wn*64 + ni*16 + cc;
        const float bv = bias ? bias[gc] : 0.f;
#pragma unroll
        for (int mi = 0; mi < 4; ++mi) {
            const int gr = bm + wm*64 + mi*16 + cr;
            float* cp = C + (size_t)gr * N + gc;
#pragma unroll
            for (int r = 0; r < 4; ++r) cp[(size_t)r * N] = acc[mi][ni][r] + bv;
        }
    }
}

extern "C" void kernel_launch(void* const* d_in, const int* in_sizes, int n_in,
                              void* d_out, int out_size, void* d_ws, size_t ws_size,
                              hipStream_t stream) {
    const int*   seq     = (const int*)d_in[0];
    const float* ctx     = (const float*)d_in[1];
    const float* emb     = (const float*)d_in[2];
    const float* W_ih    = (const float*)d_in[3];
    const float* b_ih    = (const float*)d_in[4];
    const float* W_hh    = (const float*)d_in[5];
    const float* b_hh    = (const float*)d_in[6];
    const float* W_initS = (const float*)d_in[7];
    const float* b_initS = (const float*)d_in[8];
    const float* W_initC = (const float*)d_in[9];
    const float* b_initC = (const float*)d_in[10];
    const float* W_d1    = (const float*)d_in[11];
    const float* b_d1    = (const float*)d_in[12];
    const float* W_d2    = (const float*)d_in[13];
    const float* b_d2    = (const float*)d_in[14];
    float* out = (float*)d_out;

    // workspace layout (~100 MiB)
    char* ws = (char*)d_ws;
    __bf16* Whh_bf  = (__bf16*)(ws + 0);                    //  8 MiB (reused as hid later)
    __bf16* WihE_bf = (__bf16*)(ws + (8u << 20));           //  4 MiB
    __bf16* Wd1_bf  = (__bf16*)(ws + (12u << 20));          //  4 MiB
    __bf16* Wd2_bf  = (__bf16*)(ws + (16u << 20));          //  62.5 MiB -> ends 82313216
    __bf16* X_bf    = (__bf16*)(ws + 82313216u);            //  4 MiB   -> 86507520
    float*  ctxg    = (float*) (ws + 86507520u);            //  1 MiB   -> 87556096
    float*  cbuf    = (float*) (ws + 87556096u);            //  256 KiB -> 87818240
    __bf16* HCx     = (__bf16*)(ws + 87818240u);            //  [65][64][2048] bf16 -> 104857600
    unsigned* bar   = (unsigned*)(ws + 104857600u);         //  4 KiB barrier counters
    __bf16* hid     = (__bf16*)(ws + 0);                    //  aliases Whh_bf (dead after k_rnn)

    // one-time precompute
    k_cast<<<4096, 256, 0, stream>>>(W_hh, Whh_bf, 1048576);
    k_cast_wihe<<<2048, 256, 0, stream>>>(W_ih, WihE_bf);
    k_cast<<<2048, 256, 0, stream>>>(W_d1, Wd1_bf, 524288);
    k_cast<<<32000, 256, 0, stream>>>(W_d2, Wd2_bf, 8192000);
    k_gather_x<<<2048, 256, 0, stream>>>(seq, emb, X_bf);
    k_init<<<128, 256, 0, stream>>>(ctx, W_initS, b_initS, W_initC, b_initC, HCx, cbuf);
    k_ctxgates<<<256, 256, 0, stream>>>(ctx, W_ih, b_ih, b_hh, ctxg);
    k_zero<<<1, 1024, 0, stream>>>(bar);

    // whole recurrence in ONE persistent kernel (weights + c-state in registers)
    k_rnn<<<NRB, 512, 0, stream>>>(Whh_bf, WihE_bf, X_bf, ctxg, cbuf, HCx, bar);

    // batched d1: hid[T*B, H] = tanh(HC[T*B, 2H] @ W_d1^T + b_d1); skip HCx slot 0
    k_gemm_d1<<<(H_ / 128) * ((T_ * B_) / 128), 256, 0, stream>>>(
        HCx + (size_t)B_ * 2 * H_, Wd1_bf, b_d1, hid, T_ * B_, H_, 2 * H_);

    // out[T*B, V] = hid @ W_d2^T + b_d2
    k_gemm_bt<<<(V_ / 128) * ((T_ * B_) / 128), 256, 0, stream>>>(
        hid, Wd2_bf, b_d2, out, T_ * B_, V_, H_);
}

// Round 4
// 1853.828 us; speedup vs baseline: 1.8179x; 1.0860x over previous
//
#include <hip/hip_runtime.h>
#include <hip/hip_bf16.h>
#include <cstdint>

// Problem constants
#define V_  32000
#define E_  512
#define H_  1024
#define CTX_ 1024
#define T_  64
#define B_  64
#define FH_ 4096   // 4*H
#define NRB 128    // persistent recurrence blocks (<= 256 CUs -> co-resident)

typedef __attribute__((ext_vector_type(8))) __bf16 bf16x8;
typedef __attribute__((ext_vector_type(4))) __bf16 bf16x4;
typedef __attribute__((ext_vector_type(4))) float f32x4;

#define DEV static __device__ __forceinline__

DEV __bf16 f2bf(float f) {
    union { float f; unsigned u; } v; v.f = f;
    unsigned r = (v.u + 0x7FFFu + ((v.u >> 16) & 1u)) >> 16;
    unsigned short s = (unsigned short)r;
    return __builtin_bit_cast(__bf16, s);
}

DEV float sigm(float x) { return 1.0f / (1.0f + __expf(-x)); }

// coherent (agent-scope, sc1 -> write-through to LLC) 8B store
DEV void st8cc(__bf16* p, unsigned long long v) {
    __hip_atomic_store((unsigned long long*)p, v,
                       __ATOMIC_RELAXED, __HIP_MEMORY_SCOPE_AGENT);
}

// async global->LDS, 16B per lane; LDS dest = wave-uniform base + lane*16
#define GL(g, l) __builtin_amdgcn_global_load_lds(                         \
    (const __attribute__((address_space(1))) void*)(g),                    \
    (__attribute__((address_space(3))) void*)(l), 16, 0, 0)

// ---------------- casts / gathers ----------------
__global__ __launch_bounds__(256) void k_cast(const float* __restrict__ src,
                                              __bf16* __restrict__ dst, int n4) {
    int i = blockIdx.x * 256 + threadIdx.x;
    if (i >= n4) return;
    float4 v = *(const float4*)(src + (size_t)i * 4);
    bf16x4 o; o[0]=f2bf(v.x); o[1]=f2bf(v.y); o[2]=f2bf(v.z); o[3]=f2bf(v.w);
    *(bf16x4*)(dst + (size_t)i * 4) = o;
}

// W_ihE = bf16(W_ih[:, CTX:CTX+E])  -> [4096][512]
__global__ __launch_bounds__(256) void k_cast_wihe(const float* __restrict__ Wih,
                                                   __bf16* __restrict__ dst) {
    int i = blockIdx.x * 256 + threadIdx.x;   // 524288 threads, 4 elems each
    int e = i * 4, j = e >> 9, k = e & 511;
    float4 v = *(const float4*)(Wih + (size_t)j * (CTX_ + E_) + CTX_ + k);
    bf16x4 o; o[0]=f2bf(v.x); o[1]=f2bf(v.y); o[2]=f2bf(v.z); o[3]=f2bf(v.w);
    *(bf16x4*)(dst + (size_t)e) = o;
}

// X[t*64+b][k] = bf16(emb[seq[t*64+b]][k])  -> [4096][512]
__global__ __launch_bounds__(256) void k_gather_x(const int* __restrict__ seq,
                                                  const float* __restrict__ emb,
                                                  __bf16* __restrict__ dst) {
    int i = blockIdx.x * 256 + threadIdx.x;
    int e = i * 4, r = e >> 9, k = e & 511;
    int tok = seq[r];
    float4 v = *(const float4*)(emb + (size_t)tok * E_ + k);
    bf16x4 o; o[0]=f2bf(v.x); o[1]=f2bf(v.y); o[2]=f2bf(v.z); o[3]=f2bf(v.w);
    *(bf16x4*)(dst + (size_t)e) = o;
}

// ---------------- init state: h0 -> HCx[0] h-part (stride 2048), c0 (f32) ----------------
__global__ __launch_bounds__(256) void k_init(const float* __restrict__ ctx,
                                              const float* __restrict__ WS, const float* __restrict__ bS,
                                              const float* __restrict__ WC, const float* __restrict__ bC,
                                              __bf16* __restrict__ h0, float* __restrict__ c0) {
    int idx = blockIdx.x * 256 + threadIdx.x;   // 32768
    int r = idx >> 4, bg = idx & 15;
    int sel = r >> 10, u = r & 1023;
    const float4* w = (const float4*)((sel ? WC : WS) + (size_t)u * CTX_);
    float acc[4] = {0.f,0.f,0.f,0.f};
    for (int k = 0; k < 256; ++k) {
        float4 wv = w[k];
#pragma unroll
        for (int i = 0; i < 4; ++i) {
            float4 cv = *(const float4*)(ctx + (size_t)(bg + 16*i) * CTX_ + k * 4);
            acc[i] += wv.x*cv.x + wv.y*cv.y + wv.z*cv.z + wv.w*cv.w;
        }
    }
    float bias = sel ? bC[u] : bS[u];
#pragma unroll
    for (int i = 0; i < 4; ++i) {
        int b = bg + 16*i;
        float v = tanhf(acc[i] + bias);
        if (sel) c0[(size_t)b * H_ + u] = v;
        else     h0[(size_t)b * 2048 + u] = f2bf(v);   // into HCx[0][b][u]
    }
}

// ---------------- ctx_gates[b][j] = ctx[b]·W_ih[j][0:CTX] + b_ih[j] + b_hh[j] ----------------
__global__ __launch_bounds__(256) void k_ctxgates(const float* __restrict__ ctx,
                                                  const float* __restrict__ Wih,
                                                  const float* __restrict__ bih,
                                                  const float* __restrict__ bhh,
                                                  float* __restrict__ out) {
    int idx = blockIdx.x * 256 + threadIdx.x;   // 65536
    int j = idx >> 4, bg = idx & 15;
    const float4* w = (const float4*)(Wih + (size_t)j * (CTX_ + E_));
    float acc[4] = {0.f,0.f,0.f,0.f};
    for (int k = 0; k < 256; ++k) {
        float4 wv = w[k];
#pragma unroll
        for (int i = 0; i < 4; ++i) {
            float4 cv = *(const float4*)(ctx + (size_t)(bg + 16*i) * CTX_ + k * 4);
            acc[i] += wv.x*cv.x + wv.y*cv.y + wv.z*cv.z + wv.w*cv.w;
        }
    }
    float bias = bih[j] + bhh[j];
#pragma unroll
    for (int i = 0; i < 4; ++i) out[(size_t)(bg + 16*i) * FH_ + j] = acc[i] + bias;
}

// ---------------- barrier state zero ----------------
__global__ __launch_bounds__(256) void k_zero(unsigned* __restrict__ bar, int n) {
    int i = blockIdx.x * 256 + threadIdx.x;
    if (i < n) bar[i] = 0u;
}

// ---------------- persistent recurrence kernel ----------------
// 128 blocks x 512 threads. Block owns u in [blockIdx*8, blockIdx*8+8)
// (32 gate cols: 4 gates x 8 units). Weights in registers: wave w owns
// h K-slice [w*128, w*128+128) and X K-slice [w*64, w*64+64).
// State HCx = [T+1][B][2H] bf16; step t reads slot t, writes slot t+1.
// Coherence WITHOUT per-step fences: fresh-address argument — slot t+1
// lines are never referenced by any cache before the sc1 write-through
// stores land at LLC (vmcnt drained before arrive), so plain cached loads
// at step t+1 must miss L2 and fetch fresh data (MSHR-merged per XCD).
// Barrier: two-level arrive tree (16 groups of 8 -> root), relaxed sc1
// atomics; next step's X-part GEMM overlaps barrier propagation.
__global__ __launch_bounds__(512, 2) void k_rnn(
    const __bf16* __restrict__ Whh, const __bf16* __restrict__ WihE,
    const __bf16* __restrict__ Xb, const float* __restrict__ ctxg,
    const float* __restrict__ c0,
    __bf16* __restrict__ HCx, unsigned* __restrict__ bar)
{
    __shared__ float red[8][64][36];   // partial-sum exchange
    __shared__ __bf16 hnb[64][8];      // repack for coalesced 8B coherent stores
    __shared__ __bf16 cnb[64][8];
    const int tid = threadIdx.x;
    const int w = tid >> 6, lane = tid & 63;
    const int fr = lane & 15, fq = lane >> 4;
    const int u0 = (int)blockIdx.x * 8;
    const int kh  = w * 128;           // this wave's h K-slice base (of 1024)
    const int kxo = w * 64;            // this wave's X col base (of 512)

    // ---- one-time: B fragments into registers (48 VGPRs) ----
    bf16x8 bregh[2][4], bregx[2][2];
#pragma unroll
    for (int ni = 0; ni < 2; ++ni) {
        const int n = ni * 16 + fr;                       // output col 0..31
        const int j = (n >> 3) * H_ + u0 + (n & 7);       // gate row in [0,4096)
#pragma unroll
        for (int ks = 0; ks < 4; ++ks)
            bregh[ni][ks] = *(const bf16x8*)(Whh + (size_t)j * H_ + kh + ks * 32 + fq * 8);
#pragma unroll
        for (int ks = 0; ks < 2; ++ks)
            bregx[ni][ks] = *(const bf16x8*)(WihE + (size_t)j * E_ + kxo + ks * 32 + fq * 8);
    }
    // ---- one-time: cell state + ctx-gate biases into registers ----
    const int cb = tid >> 3, cul = tid & 7, u = u0 + cul;
    float creg = c0[(size_t)cb * H_ + u];
    float cg[4];
#pragma unroll
    for (int g = 0; g < 4; ++g) cg[g] = ctxg[(size_t)cb * FH_ + g * H_ + u];

    f32x4 acc[4][2];
#pragma unroll
    for (int mi = 0; mi < 4; ++mi)
#pragma unroll
        for (int ni = 0; ni < 2; ++ni) acc[mi][ni] = (f32x4){0.f,0.f,0.f,0.f};

    // prologue: X-part of step 0
#pragma unroll
    for (int ks = 0; ks < 2; ++ks) {
        bf16x8 af[4];
#pragma unroll
        for (int mi = 0; mi < 4; ++mi)
            af[mi] = *(const bf16x8*)(Xb + (size_t)(mi * 16 + fr) * E_ + kxo + ks * 32 + fq * 8);
#pragma unroll
        for (int mi = 0; mi < 4; ++mi)
#pragma unroll
            for (int ni = 0; ni < 2; ++ni)
                acc[mi][ni] = __builtin_amdgcn_mfma_f32_16x16x32_bf16(
                    af[mi], bregx[ni][ks], acc[mi][ni], 0, 0, 0);
    }

    const int grp = (int)blockIdx.x >> 3;   // 16 groups of 8 blocks

#pragma unroll 1
    for (int t = 0; t < T_; ++t) {
        if (t > 0) {
            // spin on previous step's root (sc1 load, bypasses L2)
            if (tid == 0) {
                unsigned* rp = bar + (size_t)(t - 1) * 272 + 256;
                while (__hip_atomic_load(rp, __ATOMIC_RELAXED, __HIP_MEMORY_SCOPE_AGENT)
                       < (unsigned)(NRB / 8)) { }
            }
            __syncthreads();
        }
        const __bf16* hprev = HCx + (size_t)t * (B_ * 2 * H_);
        __bf16*       hcur  = HCx + (size_t)(t + 1) * (B_ * 2 * H_);

        // h-part GEMM over this wave's K-slice (plain cached loads; fresh
        // lines by construction, L2-shared across the XCD's blocks)
#pragma unroll
        for (int ks = 0; ks < 4; ++ks) {
            bf16x8 af[4];
#pragma unroll
            for (int mi = 0; mi < 4; ++mi)
                af[mi] = *(const bf16x8*)(hprev + (size_t)(mi * 16 + fr) * 2048 + kh + ks * 32 + fq * 8);
#pragma unroll
            for (int mi = 0; mi < 4; ++mi)
#pragma unroll
                for (int ni = 0; ni < 2; ++ni)
                    acc[mi][ni] = __builtin_amdgcn_mfma_f32_16x16x32_bf16(
                        af[mi], bregh[ni][ks], acc[mi][ni], 0, 0, 0);
        }
        // partials -> LDS  (C/D frag: col=lane&15, row=fq*4+r)
#pragma unroll
        for (int mi = 0; mi < 4; ++mi)
#pragma unroll
            for (int ni = 0; ni < 2; ++ni)
#pragma unroll
                for (int r = 0; r < 4; ++r)
                    red[w][mi * 16 + fq * 4 + r][ni * 16 + fr] = acc[mi][ni][r];
        __syncthreads();

        // 8-way reduce + fused cell update; thread owns (cb, cul)
        float gv[4];
#pragma unroll
        for (int g = 0; g < 4; ++g) {
            float s = cg[g];
#pragma unroll
            for (int wv = 0; wv < 8; ++wv) s += red[wv][cb][g * 8 + cul];
            gv[g] = s;
        }
        const float cn = sigm(gv[1]) * creg + sigm(gv[0]) * tanhf(gv[2]);
        const float hn = sigm(gv[3]) * tanhf(cn);
        creg = cn;
        hnb[cb][cul] = f2bf(hn);
        cnb[cb][cul] = f2bf(cn);
        __syncthreads();

        // coalesced coherent stores: 256 x 8B covers [64 rows][8 units] x {h,c}
        if (tid < 256) {
            const int b = tid >> 2, sel = (tid >> 1) & 1, hf = tid & 1;
            const __bf16* s = sel ? &cnb[b][hf * 4] : &hnb[b][hf * 4];
            unsigned long long q = *(const unsigned long long*)s;
            st8cc(hcur + (size_t)b * 2048 + sel * H_ + u0 + hf * 4, q);
        }
        __syncthreads();   // vmcnt drain: sc1 stores at LLC before arrive

        // two-level arrive (relaxed sc1 atomics; counters per-step, fresh)
        if (tid == 0) {
            unsigned* bs = bar + (size_t)t * 272;
            unsigned old = __hip_atomic_fetch_add(bs + grp * 16, 1u,
                               __ATOMIC_RELAXED, __HIP_MEMORY_SCOPE_AGENT);
            if (old == 7u)   // 8th arriver of the group promotes to root
                __hip_atomic_fetch_add(bs + 256, 1u,
                    __ATOMIC_RELAXED, __HIP_MEMORY_SCOPE_AGENT);
        }

        // X-part GEMM for NEXT step — overlaps barrier propagation
#pragma unroll
        for (int mi = 0; mi < 4; ++mi)
#pragma unroll
            for (int ni = 0; ni < 2; ++ni) acc[mi][ni] = (f32x4){0.f,0.f,0.f,0.f};
        if (t < T_ - 1) {
            const __bf16* Xt = Xb + (size_t)(t + 1) * (B_ * E_);
#pragma unroll
            for (int ks = 0; ks < 2; ++ks) {
                bf16x8 af[4];
#pragma unroll
                for (int mi = 0; mi < 4; ++mi)
                    af[mi] = *(const bf16x8*)(Xt + (size_t)(mi * 16 + fr) * E_ + kxo + ks * 32 + fq * 8);
#pragma unroll
                for (int mi = 0; mi < 4; ++mi)
#pragma unroll
                    for (int ni = 0; ni < 2; ++ni)
                        acc[mi][ni] = __builtin_amdgcn_mfma_f32_16x16x32_bf16(
                            af[mi], bregx[ni][ks], acc[mi][ni], 0, 0, 0);
            }
        }
    }
}

// XCD-aware tile remap for 1D-grid GEMMs: xcd = bid%8 owns an M-chunk of
// (nty/8) row-tiles; sweeps N with each B-tile reused by the chunk's tiles.
DEV void xcd_tiles(int bid, int ntx, int nty, int& x, int& y) {
    const int xcd = bid & 7, i = bid >> 3;
    const int cy = nty >> 3;            // row-tiles per XCD (nty % 8 == 0)
    x = i / cy;
    y = xcd * cy + (i % cy);
}

// ---------------- d1 GEMM (batched over all t): hid = tanh(HC @ Wd1^T + b) -> bf16 ----------------
__global__ __launch_bounds__(256) void k_gemm_d1(const __bf16* __restrict__ A,
                                                 const __bf16* __restrict__ Bt,
                                                 const float* __restrict__ bias,
                                                 __bf16* __restrict__ C,
                                                 int M, int N, int K) {
    __shared__ __align__(16) char smem[16384];
    __bf16* Als = (__bf16*)smem;            // [128][32]
    __bf16* Bls = (__bf16*)(smem + 8192);   // [128][32]
    const int tid = threadIdx.x, lane = tid & 63, wave = tid >> 6;
    const int wm = wave >> 1, wn = wave & 1;
    int tx, ty; xcd_tiles(blockIdx.x, N >> 7, M >> 7, tx, ty);
    const int bm = ty * 128, bn = tx * 128;
    const int srow = wave * 16 + (lane >> 2);
    const int scol = (lane & 3) * 8;
    const int fr = lane & 15, fq = lane >> 4;

    f32x4 acc[4][4];
#pragma unroll
    for (int i = 0; i < 4; ++i)
#pragma unroll
        for (int j = 0; j < 4; ++j) acc[i][j] = (f32x4){0.f,0.f,0.f,0.f};

    const int nkt = K >> 5;
    for (int kt = 0; kt < nkt; ++kt) {
        const int k0 = kt << 5;
        GL(A  + (size_t)(bm + srow) * K + k0 + scol,      smem + wave * 1024);
        GL(A  + (size_t)(bm + 64 + srow) * K + k0 + scol, smem + 4096 + wave * 1024);
        GL(Bt + (size_t)(bn + srow) * K + k0 + scol,      smem + 8192 + wave * 1024);
        GL(Bt + (size_t)(bn + 64 + srow) * K + k0 + scol, smem + 12288 + wave * 1024);
        __syncthreads();
        bf16x8 af[4], bfr[4];
#pragma unroll
        for (int mi = 0; mi < 4; ++mi)
            af[mi] = *(const bf16x8*)(Als + (wm*64 + mi*16 + fr) * 32 + fq * 8);
#pragma unroll
        for (int ni = 0; ni < 4; ++ni)
            bfr[ni] = *(const bf16x8*)(Bls + (wn*64 + ni*16 + fr) * 32 + fq * 8);
#pragma unroll
        for (int mi = 0; mi < 4; ++mi)
#pragma unroll
            for (int ni = 0; ni < 4; ++ni)
                acc[mi][ni] = __builtin_amdgcn_mfma_f32_16x16x32_bf16(af[mi], bfr[ni], acc[mi][ni], 0, 0, 0);
        __syncthreads();
    }
    const int cr = fq * 4, cc = fr;
#pragma unroll
    for (int ni = 0; ni < 4; ++ni) {
        const int gc = bn + wn*64 + ni*16 + cc;
        const float bv = bias[gc];
#pragma unroll
        for (int mi = 0; mi < 4; ++mi) {
            const int gr = bm + wm*64 + mi*16 + cr;
#pragma unroll
            for (int r = 0; r < 4; ++r)
                C[(size_t)(gr + r) * N + gc] = f2bf(tanhf(acc[mi][ni][r] + bv));
        }
    }
}

// ---------------- big GEMM: C[M,N] = A[M,K] * Bt[N,K]^T + bias ----------------
__global__ __launch_bounds__(256) void k_gemm_bt(const __bf16* __restrict__ A,
                                                 const __bf16* __restrict__ Bt,
                                                 const float* __restrict__ bias,
                                                 float* __restrict__ C,
                                                 int M, int N, int K) {
    __shared__ __align__(16) char smem[16384];
    __bf16* Als = (__bf16*)smem;            // [128][32]
    __bf16* Bls = (__bf16*)(smem + 8192);   // [128][32]
    const int tid = threadIdx.x, lane = tid & 63, wave = tid >> 6;
    const int wm = wave >> 1, wn = wave & 1;
    int tx, ty; xcd_tiles(blockIdx.x, N >> 7, M >> 7, tx, ty);
    const int bm = ty * 128, bn = tx * 128;
    const int srow = wave * 16 + (lane >> 2);
    const int scol = (lane & 3) * 8;
    const int fr = lane & 15, fq = lane >> 4;

    f32x4 acc[4][4];
#pragma unroll
    for (int i = 0; i < 4; ++i)
#pragma unroll
        for (int j = 0; j < 4; ++j) acc[i][j] = (f32x4){0.f,0.f,0.f,0.f};

    const int nkt = K >> 5;
    for (int kt = 0; kt < nkt; ++kt) {
        const int k0 = kt << 5;
        GL(A  + (size_t)(bm + srow) * K + k0 + scol,      smem + wave * 1024);
        GL(A  + (size_t)(bm + 64 + srow) * K + k0 + scol, smem + 4096 + wave * 1024);
        GL(Bt + (size_t)(bn + srow) * K + k0 + scol,      smem + 8192 + wave * 1024);
        GL(Bt + (size_t)(bn + 64 + srow) * K + k0 + scol, smem + 12288 + wave * 1024);
        __syncthreads();
        bf16x8 af[4], bfr[4];
#pragma unroll
        for (int mi = 0; mi < 4; ++mi)
            af[mi] = *(const bf16x8*)(Als + (wm*64 + mi*16 + fr) * 32 + fq * 8);
#pragma unroll
        for (int ni = 0; ni < 4; ++ni)
            bfr[ni] = *(const bf16x8*)(Bls + (wn*64 + ni*16 + fr) * 32 + fq * 8);
#pragma unroll
        for (int mi = 0; mi < 4; ++mi)
#pragma unroll
            for (int ni = 0; ni < 4; ++ni)
                acc[mi][ni] = __builtin_amdgcn_mfma_f32_16x16x32_bf16(af[mi], bfr[ni], acc[mi][ni], 0, 0, 0);
        __syncthreads();
    }
    const int cr = fq * 4, cc = fr;
#pragma unroll
    for (int ni = 0; ni < 4; ++ni) {
        const int gc = bn + wn*64 + ni*16 + cc;
        const float bv = bias ? bias[gc] : 0.f;
#pragma unroll
        for (int mi = 0; mi < 4; ++mi) {
            const int gr = bm + wm*64 + mi*16 + cr;
            float* cp = C + (size_t)gr * N + gc;
#pragma unroll
            for (int r = 0; r < 4; ++r) cp[(size_t)r * N] = acc[mi][ni][r] + bv;
        }
    }
}

extern "C" void kernel_launch(void* const* d_in, const int* in_sizes, int n_in,
                              void* d_out, int out_size, void* d_ws, size_t ws_size,
                              hipStream_t stream) {
    const int*   seq     = (const int*)d_in[0];
    const float* ctx     = (const float*)d_in[1];
    const float* emb     = (const float*)d_in[2];
    const float* W_ih    = (const float*)d_in[3];
    const float* b_ih    = (const float*)d_in[4];
    const float* W_hh    = (const float*)d_in[5];
    const float* b_hh    = (const float*)d_in[6];
    const float* W_initS = (const float*)d_in[7];
    const float* b_initS = (const float*)d_in[8];
    const float* W_initC = (const float*)d_in[9];
    const float* b_initC = (const float*)d_in[10];
    const float* W_d1    = (const float*)d_in[11];
    const float* b_d1    = (const float*)d_in[12];
    const float* W_d2    = (const float*)d_in[13];
    const float* b_d2    = (const float*)d_in[14];
    float* out = (float*)d_out;

    // workspace layout (~100.1 MiB)
    char* ws = (char*)d_ws;
    __bf16* Whh_bf  = (__bf16*)(ws + 0);                    //  8 MiB (reused as hid later)
    __bf16* WihE_bf = (__bf16*)(ws + (8u << 20));           //  4 MiB
    __bf16* Wd1_bf  = (__bf16*)(ws + (12u << 20));          //  4 MiB
    __bf16* Wd2_bf  = (__bf16*)(ws + (16u << 20));          //  62.5 MiB -> ends 82313216
    __bf16* X_bf    = (__bf16*)(ws + 82313216u);            //  4 MiB   -> 86507520
    float*  ctxg    = (float*) (ws + 86507520u);            //  1 MiB   -> 87556096
    float*  cbuf    = (float*) (ws + 87556096u);            //  256 KiB -> 87818240
    __bf16* HCx     = (__bf16*)(ws + 87818240u);            //  [65][64][2048] bf16 -> 104857600
    unsigned* bar   = (unsigned*)(ws + 104857600u);         //  64 steps x 272 u32 = 69632 B
    __bf16* hid     = (__bf16*)(ws + 0);                    //  aliases Whh_bf (dead after k_rnn)

    // one-time precompute
    k_cast<<<4096, 256, 0, stream>>>(W_hh, Whh_bf, 1048576);
    k_cast_wihe<<<2048, 256, 0, stream>>>(W_ih, WihE_bf);
    k_cast<<<2048, 256, 0, stream>>>(W_d1, Wd1_bf, 524288);
    k_cast<<<32000, 256, 0, stream>>>(W_d2, Wd2_bf, 8192000);
    k_gather_x<<<2048, 256, 0, stream>>>(seq, emb, X_bf);
    k_init<<<128, 256, 0, stream>>>(ctx, W_initS, b_initS, W_initC, b_initC, HCx, cbuf);
    k_ctxgates<<<256, 256, 0, stream>>>(ctx, W_ih, b_ih, b_hh, ctxg);
    k_zero<<<68, 256, 0, stream>>>(bar, 64 * 272);

    // whole recurrence in ONE persistent kernel (weights + c-state in registers)
    k_rnn<<<NRB, 512, 0, stream>>>(Whh_bf, WihE_bf, X_bf, ctxg, cbuf, HCx, bar);

    // batched d1: hid[T*B, H] = tanh(HC[T*B, 2H] @ W_d1^T + b_d1); skip HCx slot 0
    k_gemm_d1<<<(H_ / 128) * ((T_ * B_) / 128), 256, 0, stream>>>(
        HCx + (size_t)B_ * 2 * H_, Wd1_bf, b_d1, hid, T_ * B_, H_, 2 * H_);

    // out[T*B, V] = hid @ W_d2^T + b_d2
    k_gemm_bt<<<(V_ / 128) * ((T_ * B_) / 128), 256, 0, stream>>>(
        hid, Wd2_bf, b_d2, out, T_ * B_, V_, H_);
}